// Round 6
// baseline (107.304 us; speedup 1.0000x reference)
//
#include <hip/hip_runtime.h>
#include <hip/hip_fp16.h>
#include <math.h>

#define N      512
#define DIMC   128
#define HEADS  4
#define DH     32
#define INDC   5
#define SCALE  0.1767766952966369f   // 32^-0.5

// Virtual output rows of the fused pre-GEMM: all are (row_weights) @ x
//   rows [0,384)   : qkv   (q rows 0..127, k 128..255, v 256..383)
//   rows [384,404) : Aq[(h*5+c)]  composite weight  Wq_rows . W_ind_k
//   rows [404,424) : Ak[(h*5+c)]  composite weight  Wk_rows . W_ind_q
// rows are stored FP16 (halves attn L2 traffic; error << threshold)
#define QKV_ROWS 384
#define AQ_BASE  384
#define AK_BASE  404
#define TOT_ROWS 424
#define NROW_BLK (TOT_ROWS / 4)   // 106

// ws layout: [rows fp16: TOT_ROWS*N halves][M raw 4x32 f32][w_outT 16384 f32]
#define MHS_F    (TOT_ROWS * N / 2)      // float offset after fp16 rows
#define WOUTT_F  (MHS_F + 128)

// ------- Kernel 1: fused pre-GEMM + M + w_out transpose + out:=bias init -------
__global__ __launch_bounds__(256) void pre_kernel(const float* __restrict__ w_qkv,
                                                  const float* __restrict__ w_ind,
                                                  const float* __restrict__ x,
                                                  const float* __restrict__ w_out,
                                                  const float* __restrict__ b_out,
                                                  float* __restrict__ out,
                                                  float* __restrict__ ws) {
    const int bx = blockIdx.x;
    const int t  = threadIdx.x;
    __half* rows  = (__half*)ws;
    float* MhS    = ws + MHS_F;
    float* w_outT = ws + WOUTT_F;

    if (bx == NROW_BLK + 1) {
        // --- init out[:, i] = b_out (attn blocks atomicAdd their head partials) ---
        const int i = blockIdx.y * 256 + t;
        for (int o = 0; o < DIMC; ++o) out[o * N + i] = b_out[o];
        return;
    }
    if (bx == NROW_BLK) {
        if (blockIdx.y != 0) return;
        // --- M[h,c,cc] = sum_d w_ind_q[h,d,c] * w_ind_k[h,d,cc] (raw 5x5) ---
        if (t < HEADS * INDC * INDC) {
            const int h = t / 25, idx = t % 25, c = idx / 5, cc = idx % 5;
            float acc = 0.f;
            for (int d = 0; d < DH; ++d)
                acc = fmaf(w_ind[(h * DH + d) * INDC + c],
                           w_ind[(DIMC + h * DH + d) * INDC + cc], acc);
            MhS[h * 32 + idx] = acc;
        }
        // --- transpose w_out (128x128) so the fused outproj reads coalesced ---
        for (int idx = t; idx < DIMC * DIMC; idx += 256) {
            const int o = idx >> 7, c = idx & 127;
            w_outT[c * DIMC + o] = w_out[idx];
        }
        return;
    }

    // --- 4 virtual rows per block, c-major float4 layout in LDS ---
    __shared__ float ws2[4 * DIMC];   // ws2[c*4 + r]
    const int o0 = bx * 4;
    for (int idx = t; idx < 4 * DIMC; idx += 256) {
        const int r = idx & 3, m = idx >> 2;
        const int row = o0 + r;
        float val;
        if (row < QKV_ROWS) {
            val = w_qkv[row * DIMC + m];
        } else if (row < AK_BASE) {              // Aq composite: q-rows . W_ind_k
            const int rr = row - AQ_BASE, h = rr / INDC, c = rr % INDC;
            float acc = 0.f;
            for (int d = 0; d < DH; ++d)
                acc = fmaf(w_qkv[(h * DH + d) * DIMC + m],
                           w_ind[(DIMC + h * DH + d) * INDC + c], acc);
            val = acc;
        } else {                                  // Ak composite: k-rows . W_ind_q
            const int rr = row - AK_BASE, h = rr / INDC, c = rr % INDC;
            float acc = 0.f;
            for (int d = 0; d < DH; ++d)
                acc = fmaf(w_qkv[(DIMC + h * DH + d) * DIMC + m],
                           w_ind[(h * DH + d) * INDC + c], acc);
            val = acc;
        }
        ws2[m * 4 + r] = val;
    }
    __syncthreads();

    const int i = blockIdx.y * 256 + t;
    float acc[4] = {0.f, 0.f, 0.f, 0.f};
#pragma unroll 8
    for (int c = 0; c < DIMC; ++c) {
        const float xv = x[c * N + i];
        const float4 wv = *(const float4*)(ws2 + c * 4);
        acc[0] = fmaf(wv.x, xv, acc[0]);
        acc[1] = fmaf(wv.y, xv, acc[1]);
        acc[2] = fmaf(wv.z, xv, acc[2]);
        acc[3] = fmaf(wv.w, xv, acc[3]);
    }
#pragma unroll
    for (int r = 0; r < 4; ++r) rows[(o0 + r) * N + i] = __float2half(acc[r]);
}

// -- Kernel 2: one block per (i-pair, head): sim + softmax + PV + partial outproj --
// 1024 blocks (4/CU) fixes the 1-block/CU latency serialization seen in R5.
__global__ __launch_bounds__(256) void attn_kernel(const float* __restrict__ ws,
                                                   const float* __restrict__ ind,
                                                   float* __restrict__ out) {
    const int i0   = blockIdx.x * 2;
    const int h    = blockIdx.y;
    const int t    = threadIdx.x;
    const int lane = t & 63;
    const int wave = t >> 6;

    const __half* rows  = (const __half*)ws;
    const float* MhS    = ws + MHS_F;
    const float* w_outT = ws + WOUTT_F;

    const __half* q  = rows;
    const __half* Aq = rows + 3 * DIMC * N;

    __shared__ float qs[2][DH];
    __shared__ float aqs[2][INDC];
    __shared__ float ms[INDC * INDC];
    __shared__ float ps[2][N];          // 4 KB
    __shared__ float red4[2][2][4];
    __shared__ float attv[2][DH];

    if (t < DH)            qs[0][t]      = __half2float(q[(h * DH + t) * N + i0]);
    else if (t < 2 * DH)   qs[1][t - DH] = __half2float(q[(h * DH + t - DH) * N + i0 + 1]);
    else if (t < 2 * DH + INDC)
        aqs[0][t - 2 * DH] = __half2float(Aq[(h * INDC + t - 2 * DH) * N + i0]);
    else if (t < 2 * DH + 2 * INDC)
        aqs[1][t - 2 * DH - INDC] = __half2float(Aq[(h * INDC + t - 2 * DH - INDC) * N + i0 + 1]);
    else if (t >= 96 && t < 96 + 25)
        ms[t - 96] = MhS[h * 32 + (t - 96)];
    __syncthreads();

    // ---- sim for this head, both i; thread t owns j-pair (2t, 2t+1) ----
    float2 ic0[INDC], ic1[INDC];
#pragma unroll
    for (int c = 0; c < INDC; ++c) {
        ic0[c] = ((const float2*)(ind + (c * N + i0) * N))[t];
        ic1[c] = ((const float2*)(ind + (c * N + i0 + 1) * N))[t];
    }

    const __half2* k2  = (const __half2*)(rows + DIMC * N);
    const __half2* Ak2 = (const __half2*)(rows + (3 * DIMC + HEADS * INDC) * N);

    float2 qk0 = {0.f, 0.f}, qk1 = {0.f, 0.f};
#pragma unroll
    for (int d = 0; d < DH; ++d) {
        const float2 kv = __half22float2(k2[(h * DH + d) * 256 + t]);
        const float q0 = qs[0][d], q1 = qs[1][d];
        qk0.x = fmaf(q0, kv.x, qk0.x); qk0.y = fmaf(q0, kv.y, qk0.y);
        qk1.x = fmaf(q1, kv.x, qk1.x); qk1.y = fmaf(q1, kv.y, qk1.y);
    }
    float2 lin0 = {0.f, 0.f}, lin1 = {0.f, 0.f};
#pragma unroll
    for (int c = 0; c < INDC; ++c) {
        const float2 akv = __half22float2(Ak2[(h * INDC + c) * 256 + t]);
        const float a0 = aqs[0][c], a1 = aqs[1][c];
        lin0.x = fmaf(a0 + akv.x, ic0[c].x, lin0.x);
        lin0.y = fmaf(a0 + akv.y, ic0[c].y, lin0.y);
        lin1.x = fmaf(a1 + akv.x, ic1[c].x, lin1.x);
        lin1.y = fmaf(a1 + akv.y, ic1[c].y, lin1.y);
    }
    float2 qd0 = {0.f, 0.f}, qd1 = {0.f, 0.f};
#pragma unroll
    for (int c = 0; c < INDC; ++c) {
        float2 t0 = {0.f, 0.f}, t1 = {0.f, 0.f};
#pragma unroll
        for (int cc = 0; cc < INDC; ++cc) {
            const float mv = ms[c * INDC + cc];
            t0.x = fmaf(mv, ic0[cc].x, t0.x); t0.y = fmaf(mv, ic0[cc].y, t0.y);
            t1.x = fmaf(mv, ic1[cc].x, t1.x); t1.y = fmaf(mv, ic1[cc].y, t1.y);
        }
        qd0.x = fmaf(ic0[c].x, t0.x, qd0.x); qd0.y = fmaf(ic0[c].y, t0.y, qd0.y);
        qd1.x = fmaf(ic1[c].x, t1.x, qd1.x); qd1.y = fmaf(ic1[c].y, t1.y, qd1.y);
    }
    const float s0x = SCALE * (qk0.x + lin0.x + qd0.x);
    const float s0y = SCALE * (qk0.y + lin0.y + qd0.y);
    const float s1x = SCALE * (qk1.x + lin1.x + qd1.x);
    const float s1y = SCALE * (qk1.y + lin1.y + qd1.y);

    // ---- softmax over 512 per i ----
    float m0 = fmaxf(s0x, s0y), m1 = fmaxf(s1x, s1y);
#pragma unroll
    for (int off = 32; off; off >>= 1) {
        m0 = fmaxf(m0, __shfl_down(m0, off, 64));
        m1 = fmaxf(m1, __shfl_down(m1, off, 64));
    }
    if (lane == 0) { red4[0][0][wave] = m0; red4[0][1][wave] = m1; }
    __syncthreads();
    m0 = fmaxf(fmaxf(red4[0][0][0], red4[0][0][1]), fmaxf(red4[0][0][2], red4[0][0][3]));
    m1 = fmaxf(fmaxf(red4[0][1][0], red4[0][1][1]), fmaxf(red4[0][1][2], red4[0][1][3]));
    const float e0x = __expf(s0x - m0), e0y = __expf(s0y - m0);
    const float e1x = __expf(s1x - m1), e1y = __expf(s1y - m1);
    float su0 = e0x + e0y, su1 = e1x + e1y;
#pragma unroll
    for (int off = 32; off; off >>= 1) {
        su0 += __shfl_down(su0, off, 64);
        su1 += __shfl_down(su1, off, 64);
    }
    __syncthreads();   // reads of red4[0] done before rewrite
    if (lane == 0) { red4[1][0][wave] = su0; red4[1][1][wave] = su1; }
    __syncthreads();
    su0 = (red4[1][0][0] + red4[1][0][1]) + (red4[1][0][2] + red4[1][0][3]);
    su1 = (red4[1][1][0] + red4[1][1][1]) + (red4[1][1][2] + red4[1][1][3]);
    const float r0 = 1.f / su0, r1 = 1.f / su1;
    ((float2*)&ps[0][0])[t] = make_float2(e0x * r0, e0y * r0);
    ((float2*)&ps[1][0])[t] = make_float2(e1x * r1, e1y * r1);
    __syncthreads();

    // ---- PV: wave w owns d in [w*8, w*8+8); lanes split j (float2 pairs) ----
    {
        float acc0[8], acc1[8];
#pragma unroll
        for (int dd = 0; dd < 8; ++dd) { acc0[dd] = 0.f; acc1[dd] = 0.f; }
        const float2* ps0 = (const float2*)&ps[0][0];
        const float2* ps1 = (const float2*)&ps[1][0];
        const __half2* v2 = (const __half2*)(rows + 2 * DIMC * N);
        for (int s = 0; s < 4; ++s) {
            const float2 p0 = ps0[lane + 64 * s];
            const float2 p1 = ps1[lane + 64 * s];
#pragma unroll
            for (int dd = 0; dd < 8; ++dd) {
                const float2 vv =
                    __half22float2(v2[(h * DH + wave * 8 + dd) * 256 + lane + 64 * s]);
                acc0[dd] = fmaf(p0.x, vv.x, fmaf(p0.y, vv.y, acc0[dd]));
                acc1[dd] = fmaf(p1.x, vv.x, fmaf(p1.y, vv.y, acc1[dd]));
            }
        }
#pragma unroll
        for (int dd = 0; dd < 8; ++dd) {
            float a0 = acc0[dd], a1 = acc1[dd];
#pragma unroll
            for (int off = 32; off; off >>= 1) {
                a0 += __shfl_down(a0, off, 64);
                a1 += __shfl_down(a1, off, 64);
            }
            if (lane == 0) { attv[0][wave * 8 + dd] = a0; attv[1][wave * 8 + dd] = a1; }
        }
    }
    __syncthreads();

    // ---- partial output projection: out[:, i0+ii] += w_out[:, h-slice] @ attv[ii] ----
    {
        const int o = t & 127, ii = t >> 7;
        float acc = 0.f;
#pragma unroll 8
        for (int cc = 0; cc < DH; ++cc)
            acc = fmaf(w_outT[(h * DH + cc) * DIMC + o], attv[ii][cc], acc);
        atomicAdd(&out[o * N + i0 + ii], acc);
    }
}

extern "C" void kernel_launch(void* const* d_in, const int* in_sizes, int n_in,
                              void* d_out, int out_size, void* d_ws, size_t ws_size,
                              hipStream_t stream) {
    const float* x         = (const float*)d_in[0];  // (1,128,512)
    const float* indicator = (const float*)d_in[1];  // (1,5,512,512)
    const float* w_qkv     = (const float*)d_in[2];  // (384,128)
    const float* w_ind     = (const float*)d_in[3];  // (256,5)
    const float* w_out     = (const float*)d_in[4];  // (128,128)
    const float* b_out     = (const float*)d_in[5];  // (128,)
    float* out = (float*)d_out;                      // (1,128,512)
    float* ws  = (float*)d_ws;

    pre_kernel<<<dim3(NROW_BLK + 2, 2), 256, 0, stream>>>(w_qkv, w_ind, x, w_out,
                                                          b_out, out, ws);
    attn_kernel<<<dim3(N / 2, HEADS), 256, 0, stream>>>(ws, indicator, out);
}

// Round 7
// 103.407 us; speedup vs baseline: 1.0377x; 1.0377x over previous
//
#include <hip/hip_runtime.h>
#include <hip/hip_fp16.h>
#include <math.h>

#define N      512
#define DIMC   128
#define HEADS  4
#define DH     32
#define INDC   5
#define SCALE  0.1767766952966369f   // 32^-0.5

// Virtual output rows of the fused pre-GEMM: all are (row_weights) @ x
//   rows [0,384)   : qkv   (q rows 0..127, k 128..255, v 256..383)
//   rows [384,404) : Aq[(h*5+c)]  composite weight  Wq_rows . W_ind_k
//   rows [404,424) : Ak[(h*5+c)]  composite weight  Wk_rows . W_ind_q
// rows are stored FP16 (halves attn L2 traffic; error << threshold)
#define QKV_ROWS 384
#define AQ_BASE  384
#define AK_BASE  404
#define TOT_ROWS 424
#define NROW_BLK (TOT_ROWS / 4)   // 106

// ws layout: [rows fp16][M raw 4x32 f32][w_outT 16384 f32][att 512x128 f32]
#define MHS_F    (TOT_ROWS * N / 2)
#define WOUTT_F  (MHS_F + 128)
#define ATT_F    (WOUTT_F + DIMC * DIMC)

// ---------------- Kernel 1: fused pre-GEMM + M + w_out transpose ----------------
__global__ __launch_bounds__(256) void pre_kernel(const float* __restrict__ w_qkv,
                                                  const float* __restrict__ w_ind,
                                                  const float* __restrict__ x,
                                                  const float* __restrict__ w_out,
                                                  float* __restrict__ ws) {
    const int bx = blockIdx.x;
    const int t  = threadIdx.x;
    __half* rows  = (__half*)ws;
    float* MhS    = ws + MHS_F;
    float* w_outT = ws + WOUTT_F;

    if (bx == NROW_BLK) {
        if (blockIdx.y != 0) return;
        // --- M[h,c,cc] = sum_d w_ind_q[h,d,c] * w_ind_k[h,d,cc] (raw 5x5) ---
        if (t < HEADS * INDC * INDC) {
            const int h = t / 25, idx = t % 25, c = idx / 5, cc = idx % 5;
            float acc = 0.f;
            for (int d = 0; d < DH; ++d)
                acc = fmaf(w_ind[(h * DH + d) * INDC + c],
                           w_ind[(DIMC + h * DH + d) * INDC + cc], acc);
            MhS[h * 32 + idx] = acc;
        }
        // --- transpose w_out (128x128) so outproj reads coalesced ---
        for (int idx = t; idx < DIMC * DIMC; idx += 256) {
            const int o = idx >> 7, c = idx & 127;
            w_outT[c * DIMC + o] = w_out[idx];
        }
        return;
    }

    // --- 4 virtual rows per block, c-major float4 layout in LDS ---
    __shared__ float ws2[4 * DIMC];   // ws2[c*4 + r]
    const int o0 = bx * 4;
    for (int idx = t; idx < 4 * DIMC; idx += 256) {
        const int r = idx & 3, m = idx >> 2;
        const int row = o0 + r;
        float val;
        if (row < QKV_ROWS) {
            val = w_qkv[row * DIMC + m];
        } else if (row < AK_BASE) {              // Aq composite: q-rows . W_ind_k
            const int rr = row - AQ_BASE, h = rr / INDC, c = rr % INDC;
            float acc = 0.f;
            for (int d = 0; d < DH; ++d)
                acc = fmaf(w_qkv[(h * DH + d) * DIMC + m],
                           w_ind[(DIMC + h * DH + d) * INDC + c], acc);
            val = acc;
        } else {                                  // Ak composite: k-rows . W_ind_q
            const int rr = row - AK_BASE, h = rr / INDC, c = rr % INDC;
            float acc = 0.f;
            for (int d = 0; d < DH; ++d)
                acc = fmaf(w_qkv[(DIMC + h * DH + d) * DIMC + m],
                           w_ind[(h * DH + d) * INDC + c], acc);
            val = acc;
        }
        ws2[m * 4 + r] = val;
    }
    __syncthreads();

    const int i = blockIdx.y * 256 + t;
    float acc[4] = {0.f, 0.f, 0.f, 0.f};
#pragma unroll 8
    for (int c = 0; c < DIMC; ++c) {
        const float xv = x[c * N + i];
        const float4 wv = *(const float4*)(ws2 + c * 4);
        acc[0] = fmaf(wv.x, xv, acc[0]);
        acc[1] = fmaf(wv.y, xv, acc[1]);
        acc[2] = fmaf(wv.z, xv, acc[2]);
        acc[3] = fmaf(wv.w, xv, acc[3]);
    }
#pragma unroll
    for (int r = 0; r < 4; ++r) rows[(o0 + r) * N + i] = __float2half(acc[r]);
}

// ---- Kernel 2: one block per (i-pair, head): sim + softmax + PV -> att scratch ----
// No atomics: per-head attv goes to att[i][128] contiguously; outproj combines.
__global__ __launch_bounds__(256) void attn_kernel(const float* __restrict__ ws_c,
                                                   const float* __restrict__ ind,
                                                   float* __restrict__ ws_w) {
    const int i0   = blockIdx.x * 2;
    const int h    = blockIdx.y;
    const int t    = threadIdx.x;
    const int lane = t & 63;
    const int wave = t >> 6;

    const __half* rows  = (const __half*)ws_c;
    const float* MhS    = ws_c + MHS_F;
    float* att          = ws_w + ATT_F;

    const __half* q  = rows;
    const __half* Aq = rows + 3 * DIMC * N;

    __shared__ float qs[2][DH];
    __shared__ float aqs[2][INDC];
    __shared__ float ms[INDC * INDC];
    __shared__ float ps[2][N];          // 4 KB
    __shared__ float red4[2][2][4];
    __shared__ float attv[2][DH];

    if (t < DH)            qs[0][t]      = __half2float(q[(h * DH + t) * N + i0]);
    else if (t < 2 * DH)   qs[1][t - DH] = __half2float(q[(h * DH + t - DH) * N + i0 + 1]);
    else if (t < 2 * DH + INDC)
        aqs[0][t - 2 * DH] = __half2float(Aq[(h * INDC + t - 2 * DH) * N + i0]);
    else if (t < 2 * DH + 2 * INDC)
        aqs[1][t - 2 * DH - INDC] = __half2float(Aq[(h * INDC + t - 2 * DH - INDC) * N + i0 + 1]);
    else if (t >= 96 && t < 96 + 25)
        ms[t - 96] = MhS[h * 32 + (t - 96)];
    __syncthreads();

    // ---- sim for this head, both i; thread t owns j-pair (2t, 2t+1) ----
    float2 ic0[INDC], ic1[INDC];
#pragma unroll
    for (int c = 0; c < INDC; ++c) {
        ic0[c] = ((const float2*)(ind + (c * N + i0) * N))[t];
        ic1[c] = ((const float2*)(ind + (c * N + i0 + 1) * N))[t];
    }

    const __half2* k2  = (const __half2*)(rows + DIMC * N);
    const __half2* Ak2 = (const __half2*)(rows + (3 * DIMC + HEADS * INDC) * N);

    float2 qk0 = {0.f, 0.f}, qk1 = {0.f, 0.f};
#pragma unroll
    for (int d = 0; d < DH; ++d) {
        const float2 kv = __half22float2(k2[(h * DH + d) * 256 + t]);
        const float q0 = qs[0][d], q1 = qs[1][d];
        qk0.x = fmaf(q0, kv.x, qk0.x); qk0.y = fmaf(q0, kv.y, qk0.y);
        qk1.x = fmaf(q1, kv.x, qk1.x); qk1.y = fmaf(q1, kv.y, qk1.y);
    }
    float2 lin0 = {0.f, 0.f}, lin1 = {0.f, 0.f};
#pragma unroll
    for (int c = 0; c < INDC; ++c) {
        const float2 akv = __half22float2(Ak2[(h * INDC + c) * 256 + t]);
        const float a0 = aqs[0][c], a1 = aqs[1][c];
        lin0.x = fmaf(a0 + akv.x, ic0[c].x, lin0.x);
        lin0.y = fmaf(a0 + akv.y, ic0[c].y, lin0.y);
        lin1.x = fmaf(a1 + akv.x, ic1[c].x, lin1.x);
        lin1.y = fmaf(a1 + akv.y, ic1[c].y, lin1.y);
    }
    float2 qd0 = {0.f, 0.f}, qd1 = {0.f, 0.f};
#pragma unroll
    for (int c = 0; c < INDC; ++c) {
        float2 t0 = {0.f, 0.f}, t1 = {0.f, 0.f};
#pragma unroll
        for (int cc = 0; cc < INDC; ++cc) {
            const float mv = ms[c * INDC + cc];
            t0.x = fmaf(mv, ic0[cc].x, t0.x); t0.y = fmaf(mv, ic0[cc].y, t0.y);
            t1.x = fmaf(mv, ic1[cc].x, t1.x); t1.y = fmaf(mv, ic1[cc].y, t1.y);
        }
        qd0.x = fmaf(ic0[c].x, t0.x, qd0.x); qd0.y = fmaf(ic0[c].y, t0.y, qd0.y);
        qd1.x = fmaf(ic1[c].x, t1.x, qd1.x); qd1.y = fmaf(ic1[c].y, t1.y, qd1.y);
    }
    const float s0x = SCALE * (qk0.x + lin0.x + qd0.x);
    const float s0y = SCALE * (qk0.y + lin0.y + qd0.y);
    const float s1x = SCALE * (qk1.x + lin1.x + qd1.x);
    const float s1y = SCALE * (qk1.y + lin1.y + qd1.y);

    // ---- softmax over 512 per i ----
    float m0 = fmaxf(s0x, s0y), m1 = fmaxf(s1x, s1y);
#pragma unroll
    for (int off = 32; off; off >>= 1) {
        m0 = fmaxf(m0, __shfl_down(m0, off, 64));
        m1 = fmaxf(m1, __shfl_down(m1, off, 64));
    }
    if (lane == 0) { red4[0][0][wave] = m0; red4[0][1][wave] = m1; }
    __syncthreads();
    m0 = fmaxf(fmaxf(red4[0][0][0], red4[0][0][1]), fmaxf(red4[0][0][2], red4[0][0][3]));
    m1 = fmaxf(fmaxf(red4[0][1][0], red4[0][1][1]), fmaxf(red4[0][1][2], red4[0][1][3]));
    const float e0x = __expf(s0x - m0), e0y = __expf(s0y - m0);
    const float e1x = __expf(s1x - m1), e1y = __expf(s1y - m1);
    float su0 = e0x + e0y, su1 = e1x + e1y;
#pragma unroll
    for (int off = 32; off; off >>= 1) {
        su0 += __shfl_down(su0, off, 64);
        su1 += __shfl_down(su1, off, 64);
    }
    __syncthreads();   // reads of red4[0] done before rewrite
    if (lane == 0) { red4[1][0][wave] = su0; red4[1][1][wave] = su1; }
    __syncthreads();
    su0 = (red4[1][0][0] + red4[1][0][1]) + (red4[1][0][2] + red4[1][0][3]);
    su1 = (red4[1][1][0] + red4[1][1][1]) + (red4[1][1][2] + red4[1][1][3]);
    const float r0 = 1.f / su0, r1 = 1.f / su1;
    ((float2*)&ps[0][0])[t] = make_float2(e0x * r0, e0y * r0);
    ((float2*)&ps[1][0])[t] = make_float2(e1x * r1, e1y * r1);
    __syncthreads();

    // ---- PV: wave w owns d in [w*8, w*8+8); lanes split j (float2 pairs) ----
    {
        float acc0[8], acc1[8];
#pragma unroll
        for (int dd = 0; dd < 8; ++dd) { acc0[dd] = 0.f; acc1[dd] = 0.f; }
        const float2* ps0 = (const float2*)&ps[0][0];
        const float2* ps1 = (const float2*)&ps[1][0];
        const __half2* v2 = (const __half2*)(rows + 2 * DIMC * N);
        for (int s = 0; s < 4; ++s) {
            const float2 p0 = ps0[lane + 64 * s];
            const float2 p1 = ps1[lane + 64 * s];
#pragma unroll
            for (int dd = 0; dd < 8; ++dd) {
                const float2 vv =
                    __half22float2(v2[(h * DH + wave * 8 + dd) * 256 + lane + 64 * s]);
                acc0[dd] = fmaf(p0.x, vv.x, fmaf(p0.y, vv.y, acc0[dd]));
                acc1[dd] = fmaf(p1.x, vv.x, fmaf(p1.y, vv.y, acc1[dd]));
            }
        }
#pragma unroll
        for (int dd = 0; dd < 8; ++dd) {
            float a0 = acc0[dd], a1 = acc1[dd];
#pragma unroll
            for (int off = 32; off; off >>= 1) {
                a0 += __shfl_down(a0, off, 64);
                a1 += __shfl_down(a1, off, 64);
            }
            if (lane == 0) { attv[0][wave * 8 + dd] = a0; attv[1][wave * 8 + dd] = a1; }
        }
    }
    __syncthreads();

    // ---- contiguous scratch store: att[i][h*32+d] (no atomics) ----
    if (t < 2 * DH) {
        const int ii = t >> 5, d = t & 31;
        att[(i0 + ii) * DIMC + h * DH + d] = attv[ii][d];
    }
}

// ------- Kernel 3: out[:, i] = w_out @ att[i] + b_out  (one block per i) -------
__global__ __launch_bounds__(128) void outproj_kernel(const float* __restrict__ ws,
                                                      const float* __restrict__ b_out,
                                                      float* __restrict__ out) {
    const int i = blockIdx.x;
    const int t = threadIdx.x;   // o
    const float* w_outT = ws + WOUTT_F;
    const float* att    = ws + ATT_F;
    __shared__ float av[DIMC];
    av[t] = att[i * DIMC + t];
    __syncthreads();
    float acc = 0.f;
#pragma unroll 8
    for (int c = 0; c < DIMC; ++c)
        acc = fmaf(w_outT[c * DIMC + t], av[c], acc);
    out[t * N + i] = acc + b_out[t];
}

extern "C" void kernel_launch(void* const* d_in, const int* in_sizes, int n_in,
                              void* d_out, int out_size, void* d_ws, size_t ws_size,
                              hipStream_t stream) {
    const float* x         = (const float*)d_in[0];  // (1,128,512)
    const float* indicator = (const float*)d_in[1];  // (1,5,512,512)
    const float* w_qkv     = (const float*)d_in[2];  // (384,128)
    const float* w_ind     = (const float*)d_in[3];  // (256,5)
    const float* w_out     = (const float*)d_in[4];  // (128,128)
    const float* b_out     = (const float*)d_in[5];  // (128,)
    float* out = (float*)d_out;                      // (1,128,512)
    float* ws  = (float*)d_ws;

    pre_kernel<<<dim3(NROW_BLK + 1, 2), 256, 0, stream>>>(w_qkv, w_ind, x, w_out, ws);
    attn_kernel<<<dim3(N / 2, HEADS), 256, 0, stream>>>(ws, indicator, ws);
    outproj_kernel<<<N, 128, 0, stream>>>(ws, b_out, out);
}

// Round 8
// 101.550 us; speedup vs baseline: 1.0567x; 1.0183x over previous
//
#include <hip/hip_runtime.h>
#include <hip/hip_fp16.h>
#include <math.h>

#define N      512
#define DIMC   128
#define HEADS  4
#define DH     32
#define INDC   5
#define SCALE  0.1767766952966369f   // 32^-0.5

// Virtual output rows of the fused pre-GEMM: all are (row_weights) @ x
//   rows [0,384)   : qkv   (q rows 0..127, k 128..255, v 256..383)
//   rows [384,404) : Aq[(h*5+c)]  composite weight  Wq_rows . W_ind_k
//   rows [404,424) : Ak[(h*5+c)]  composite weight  Wk_rows . W_ind_q
// rows are stored FP16 (halves attn L2 traffic; error << threshold)
#define QKV_ROWS 384
#define AQ_BASE  384
#define AK_BASE  404
#define TOT_ROWS 424
#define NROW_BLK (TOT_ROWS / 4)   // 106

// ws layout: [rows fp16][M raw 4x32 f32][w_outT 16384 f32][att 512x128 f32]
#define MHS_F    (TOT_ROWS * N / 2)
#define WOUTT_F  (MHS_F + 128)
#define ATT_F    (WOUTT_F + DIMC * DIMC)

// ---------------- Kernel 1: fused pre-GEMM + M + w_out transpose ----------------
__global__ __launch_bounds__(256) void pre_kernel(const float* __restrict__ w_qkv,
                                                  const float* __restrict__ w_ind,
                                                  const float* __restrict__ x,
                                                  const float* __restrict__ w_out,
                                                  float* __restrict__ ws) {
    const int bx = blockIdx.x;
    const int t  = threadIdx.x;
    __half* rows  = (__half*)ws;
    float* MhS    = ws + MHS_F;
    float* w_outT = ws + WOUTT_F;

    if (bx == NROW_BLK) {
        if (blockIdx.y != 0) return;
        // --- M[h,c,cc] = sum_d w_ind_q[h,d,c] * w_ind_k[h,d,cc] (raw 5x5) ---
        if (t < HEADS * INDC * INDC) {
            const int h = t / 25, idx = t % 25, c = idx / 5, cc = idx % 5;
            float acc = 0.f;
            for (int d = 0; d < DH; ++d)
                acc = fmaf(w_ind[(h * DH + d) * INDC + c],
                           w_ind[(DIMC + h * DH + d) * INDC + cc], acc);
            MhS[h * 32 + idx] = acc;
        }
        // --- transpose w_out (128x128) so outproj reads coalesced ---
        for (int idx = t; idx < DIMC * DIMC; idx += 256) {
            const int o = idx >> 7, c = idx & 127;
            w_outT[c * DIMC + o] = w_out[idx];
        }
        return;
    }

    // --- 4 virtual rows per block, c-major float4 layout in LDS ---
    __shared__ float ws2[4 * DIMC];   // ws2[c*4 + r]
    const int o0 = bx * 4;
    for (int idx = t; idx < 4 * DIMC; idx += 256) {
        const int r = idx & 3, m = idx >> 2;
        const int row = o0 + r;
        float val;
        if (row < QKV_ROWS) {
            val = w_qkv[row * DIMC + m];
        } else if (row < AK_BASE) {              // Aq composite: q-rows . W_ind_k
            const int rr = row - AQ_BASE, h = rr / INDC, c = rr % INDC;
            float acc = 0.f;
            for (int d = 0; d < DH; ++d)
                acc = fmaf(w_qkv[(h * DH + d) * DIMC + m],
                           w_ind[(DIMC + h * DH + d) * INDC + c], acc);
            val = acc;
        } else {                                  // Ak composite: k-rows . W_ind_q
            const int rr = row - AK_BASE, h = rr / INDC, c = rr % INDC;
            float acc = 0.f;
            for (int d = 0; d < DH; ++d)
                acc = fmaf(w_qkv[(DIMC + h * DH + d) * DIMC + m],
                           w_ind[(h * DH + d) * INDC + c], acc);
            val = acc;
        }
        ws2[m * 4 + r] = val;
    }
    __syncthreads();

    const int i = blockIdx.y * 256 + t;
    float acc[4] = {0.f, 0.f, 0.f, 0.f};
#pragma unroll 8
    for (int c = 0; c < DIMC; ++c) {
        const float xv = x[c * N + i];
        const float4 wv = *(const float4*)(ws2 + c * 4);
        acc[0] = fmaf(wv.x, xv, acc[0]);
        acc[1] = fmaf(wv.y, xv, acc[1]);
        acc[2] = fmaf(wv.z, xv, acc[2]);
        acc[3] = fmaf(wv.w, xv, acc[3]);
    }
#pragma unroll
    for (int r = 0; r < 4; ++r) rows[(o0 + r) * N + i] = __float2half(acc[r]);
}

// ---- Kernel 2: BARRIER-FREE wave-per-(i,h) attention ----
// Each 64-lane wave owns one (i, head): 8 j's per lane, softmax via shfl_xor,
// P staged in per-wave LDS (intra-wave, no barrier), PV with one d per lane.
// Block = 4 waves = 4 consecutive i of one head. Zero __syncthreads.
__global__ __launch_bounds__(256) void attn_kernel(const float* __restrict__ ws_c,
                                                   const float* __restrict__ ind,
                                                   float* __restrict__ ws_w) {
    const int t    = threadIdx.x;
    const int lane = t & 63;
    const int wv   = t >> 6;
    const int i    = blockIdx.x * 4 + wv;
    const int h    = blockIdx.y;

    const __half* rows = (const __half*)ws_c;
    const float*  Mh   = ws_c + MHS_F;
    float*        att  = ws_w + ATT_F;

    __shared__ float psh[4][N];   // 8 KB: per-wave P

    // ---- per-wave scalars ----
    const __half* q  = rows;
    const __half* Aq = rows + 3 * DIMC * N;
    const float qreg = __half2float(q[(h * DH + (lane & 31)) * N + i]); // lane d holds q_d
    float aq[INDC];
#pragma unroll
    for (int c = 0; c < INDC; ++c)
        aq[c] = __half2float(Aq[(h * INDC + c) * N + i]);   // same addr all lanes: broadcast
    float M[INDC * INDC];                                   // h uniform -> scalar loads
#pragma unroll
    for (int p = 0; p < INDC * INDC; ++p) M[p] = Mh[h * 32 + p];

    // ---- indicator: 8 consecutive j's per lane, 2 float4 per c ----
    float ic[INDC][8];
#pragma unroll
    for (int c = 0; c < INDC; ++c) {
        const float4* ip = (const float4*)(ind + (c * N + i) * N);
        *(float4*)&ic[c][0] = ip[lane * 2];
        *(float4*)&ic[c][4] = ip[lane * 2 + 1];
    }

    // ---- qk: 32 coalesced float4 K loads (8 halfs each) ----
    float s[8] = {0.f, 0.f, 0.f, 0.f, 0.f, 0.f, 0.f, 0.f};
    const float4* k4 = (const float4*)(rows + DIMC * N);    // row stride 64 float4
#pragma unroll
    for (int d = 0; d < DH; ++d) {
        const float qd = __shfl(qreg, d, 64);
        const float4 kv = k4[(h * DH + d) * 64 + lane];
        const __half2* kh = (const __half2*)&kv;
#pragma unroll
        for (int p = 0; p < 4; ++p) {
            const float2 kf = __half22float2(kh[p]);
            s[p * 2 + 0] = fmaf(qd, kf.x, s[p * 2 + 0]);
            s[p * 2 + 1] = fmaf(qd, kf.y, s[p * 2 + 1]);
        }
    }
    // ---- lin: (aq_c + Ak_c[j]) * ic_c[j] ----
    const float4* ak4 = (const float4*)(rows + (3 * DIMC + HEADS * INDC) * N);
#pragma unroll
    for (int c = 0; c < INDC; ++c) {
        const float4 av = ak4[(h * INDC + c) * 64 + lane];
        const __half2* ah = (const __half2*)&av;
#pragma unroll
        for (int p = 0; p < 4; ++p) {
            const float2 af = __half22float2(ah[p]);
            s[p * 2 + 0] = fmaf(aq[c] + af.x, ic[c][p * 2 + 0], s[p * 2 + 0]);
            s[p * 2 + 1] = fmaf(aq[c] + af.y, ic[c][p * 2 + 1], s[p * 2 + 1]);
        }
    }
    // ---- quad: ic^T M ic per j ----
#pragma unroll
    for (int j = 0; j < 8; ++j) {
        float acc = 0.f;
#pragma unroll
        for (int c = 0; c < INDC; ++c) {
            float tc = 0.f;
#pragma unroll
            for (int cc = 0; cc < INDC; ++cc)
                tc = fmaf(M[c * INDC + cc], ic[cc][j], tc);
            acc = fmaf(ic[c][j], tc, acc);
        }
        s[j] = SCALE * (s[j] + acc);
    }

    // ---- softmax across the wave (512 j) — pure shuffles ----
    float m = s[0];
#pragma unroll
    for (int j = 1; j < 8; ++j) m = fmaxf(m, s[j]);
#pragma unroll
    for (int off = 32; off; off >>= 1) m = fmaxf(m, __shfl_xor(m, off, 64));
    float e[8], sum = 0.f;
#pragma unroll
    for (int j = 0; j < 8; ++j) { e[j] = __expf(s[j] - m); sum += e[j]; }
#pragma unroll
    for (int off = 32; off; off >>= 1) sum += __shfl_xor(sum, off, 64);
    const float rs = 1.f / sum;
#pragma unroll
    for (int j = 0; j < 8; ++j) e[j] *= rs;

    // ---- stage P in per-wave LDS (intra-wave: no barrier needed) ----
    *(float4*)&psh[wv][lane * 8]     = make_float4(e[0], e[1], e[2], e[3]);
    *(float4*)&psh[wv][lane * 8 + 4] = make_float4(e[4], e[5], e[6], e[7]);

    // ---- PV: lane (d, half) sums its 256 j's; LDS reads broadcast ----
    const int d = lane & 31, half = lane >> 5;
    const float4* v4 = (const float4*)(rows + 2 * DIMC * N);
    const float4* pf = (const float4*)&psh[wv][0];
    float acc = 0.f;
#pragma unroll
    for (int kk = 0; kk < 32; ++kk) {
        const float4 vv = v4[(h * DH + d) * 64 + half * 32 + kk];  // 8 j's
        const float4 p0 = pf[half * 64 + kk * 2];
        const float4 p1 = pf[half * 64 + kk * 2 + 1];
        const __half2* vh = (const __half2*)&vv;
        const float2 f0 = __half22float2(vh[0]);
        const float2 f1 = __half22float2(vh[1]);
        const float2 f2 = __half22float2(vh[2]);
        const float2 f3 = __half22float2(vh[3]);
        acc = fmaf(p0.x, f0.x, acc); acc = fmaf(p0.y, f0.y, acc);
        acc = fmaf(p0.z, f1.x, acc); acc = fmaf(p0.w, f1.y, acc);
        acc = fmaf(p1.x, f2.x, acc); acc = fmaf(p1.y, f2.y, acc);
        acc = fmaf(p1.z, f3.x, acc); acc = fmaf(p1.w, f3.y, acc);
    }
    acc += __shfl_xor(acc, 32, 64);              // combine the two j-halves
    if (lane < 32) att[i * DIMC + h * DH + lane] = acc;   // coalesced 128 B
}

// ------- Kernel 3: out[:, i] = w_out @ att[i] + b_out  (one block per i) -------
__global__ __launch_bounds__(128) void outproj_kernel(const float* __restrict__ ws,
                                                      const float* __restrict__ b_out,
                                                      float* __restrict__ out) {
    const int i = blockIdx.x;
    const int t = threadIdx.x;   // o
    const float* w_outT = ws + WOUTT_F;
    const float* att    = ws + ATT_F;
    __shared__ float av[DIMC];
    av[t] = att[i * DIMC + t];
    __syncthreads();
    float acc = 0.f;
#pragma unroll 8
    for (int c = 0; c < DIMC; ++c)
        acc = fmaf(w_outT[c * DIMC + t], av[c], acc);
    out[t * N + i] = acc + b_out[t];
}

extern "C" void kernel_launch(void* const* d_in, const int* in_sizes, int n_in,
                              void* d_out, int out_size, void* d_ws, size_t ws_size,
                              hipStream_t stream) {
    const float* x         = (const float*)d_in[0];  // (1,128,512)
    const float* indicator = (const float*)d_in[1];  // (1,5,512,512)
    const float* w_qkv     = (const float*)d_in[2];  // (384,128)
    const float* w_ind     = (const float*)d_in[3];  // (256,5)
    const float* w_out     = (const float*)d_in[4];  // (128,128)
    const float* b_out     = (const float*)d_in[5];  // (128,)
    float* out = (float*)d_out;                      // (1,128,512)
    float* ws  = (float*)d_ws;

    pre_kernel<<<dim3(NROW_BLK + 1, 2), 256, 0, stream>>>(w_qkv, w_ind, x, w_out, ws);
    attn_kernel<<<dim3(N / 4, HEADS), 256, 0, stream>>>(ws, indicator, ws);
    outproj_kernel<<<N, 128, 0, stream>>>(ws, b_out, out);
}